// Round 1
// baseline (2737.426 us; speedup 1.0000x reference)
//
#include <hip/hip_runtime.h>
#include <hip/hip_bf16.h>
#include <cstdint>

// Problem constants
#define Bn 4
#define Tn 12
#define Nn 512
#define Kh 8
#define dh 64
#define Dn 512
#define K_GEO 4
#define WIN 12
#define DFT 256
#define Pn 16
#define Mrows (Bn*Tn*Nn)   // 24576

// ---------------- tiled f32 GEMM with optional concat input + relu ----------------
// C[M x 512] = relu( A[M x Ktot] @ W[Ktot x 512] + bias )
// A column kk < 512 read from A0[m*512+kk], else A1[m*512+kk-512].
#define BM 64
#define BN 64
#define BK 16
__global__ __launch_bounds__(256) void gemm_relu_kernel(
    const float* __restrict__ A0, const float* __restrict__ A1,
    const float* __restrict__ W, const float* __restrict__ bias,
    float* __restrict__ C, int Ktot) {
  __shared__ float As[BK][BM];   // As[k][m]
  __shared__ float Bs[BK][BN];   // Bs[k][n]
  const int tid = threadIdx.x;
  const int tx = tid & 15;       // 0..15 (N dim)
  const int ty = tid >> 4;       // 0..15 (M dim)
  const int row0 = blockIdx.y * BM;
  const int col0 = blockIdx.x * BN;
  float acc[4][4] = {};
  for (int k0 = 0; k0 < Ktot; k0 += BK) {
    const float* Asrc = (k0 < 512) ? A0 : A1;
    const int kk0 = (k0 < 512) ? k0 : (k0 - 512);
    // load A tile: 64 rows x 16 k  (256 float4, one per thread)
    {
      const int r  = tid >> 2;            // 0..63
      const int c4 = (tid & 3) * 4;       // 0,4,8,12
      const float4 av = *reinterpret_cast<const float4*>(
          &Asrc[(size_t)(row0 + r) * 512 + kk0 + c4]);
      As[c4 + 0][r] = av.x; As[c4 + 1][r] = av.y;
      As[c4 + 2][r] = av.z; As[c4 + 3][r] = av.w;
    }
    // load B tile: 16 k x 64 cols (256 float4)
    {
      const int r  = tid >> 4;            // 0..15
      const int c4 = (tid & 15) * 4;
      *reinterpret_cast<float4*>(&Bs[r][c4]) = *reinterpret_cast<const float4*>(
          &W[(size_t)(k0 + r) * 512 + col0 + c4]);
    }
    __syncthreads();
#pragma unroll
    for (int k = 0; k < BK; ++k) {
      float a[4], b[4];
      const float4 av = *reinterpret_cast<const float4*>(&As[k][ty * 4]);
      const float4 bv = *reinterpret_cast<const float4*>(&Bs[k][tx * 4]);
      a[0]=av.x; a[1]=av.y; a[2]=av.z; a[3]=av.w;
      b[0]=bv.x; b[1]=bv.y; b[2]=bv.z; b[3]=bv.w;
#pragma unroll
      for (int i = 0; i < 4; ++i)
#pragma unroll
        for (int j = 0; j < 4; ++j)
          acc[i][j] += a[i] * b[j];
    }
    __syncthreads();
  }
#pragma unroll
  for (int i = 0; i < 4; ++i) {
    const int r = row0 + ty * 4 + i;
#pragma unroll
    for (int j = 0; j < 4; ++j) {
      const int c = col0 + tx * 4 + j;
      float v = acc[i][j] + bias[c];
      C[(size_t)r * 512 + c] = v > 0.f ? v : 0.f;
    }
  }
}

// ---------------- scalar = X @ W_scalar  (wave per row) ----------------
__global__ __launch_bounds__(256) void scalar_kernel(
    const float* __restrict__ X, const float* __restrict__ Ws,
    float* __restrict__ out) {
  const int lane = threadIdx.x & 63;
  const int widx = threadIdx.x >> 6;
  const int row = blockIdx.x * 4 + widx;
  const float* xr = X + (size_t)row * 512;
  float d = 0.f;
#pragma unroll
  for (int h = 0; h < 2; ++h) {
    const int c = h * 256 + lane * 4;
    const float4 xv = *reinterpret_cast<const float4*>(&xr[c]);
    const float4 wv = *reinterpret_cast<const float4*>(&Ws[c]);
    d += xv.x * wv.x + xv.y * wv.y + xv.z * wv.z + xv.w * wv.w;
  }
#pragma unroll
  for (int off = 32; off; off >>= 1) d += __shfl_xor(d, off);
  if (lane == 0) out[row] = d;
}

// ---------------- mem/val = (pattern_keys @ W_pm/W_pv) ----------------
__global__ __launch_bounds__(256) void memval_kernel(
    const float* __restrict__ PK, const float* __restrict__ Wpm,
    const float* __restrict__ Wpv, float* __restrict__ mem,
    float* __restrict__ val) {
  const int p = blockIdx.x;   // 0..15
  const int f = threadIdx.x;  // 0..255
  float m = 0.f, v = 0.f;
#pragma unroll
  for (int i = 0; i < WIN; ++i) {
    const float pk = PK[p * WIN + i];
    m += pk * Wpm[i * DFT + f];
    v += pk * Wpv[i * DFT + f];
  }
  mem[p * DFT + f] = m;
  val[p * DFT + f] = v;
}

// ---------------- DFT pattern branch, adds into q channels [0,256) ----------------
__global__ __launch_bounds__(256) void dft_kernel(
    const float* __restrict__ scalar, const float* __restrict__ Wwq,
    const float* __restrict__ mem, const float* __restrict__ val,
    float* __restrict__ q) {
  const int mrow = blockIdx.x;        // 0..24575  == (b*T+t)*N + n
  const int n = mrow & (Nn - 1);
  const int bt = mrow >> 9;           // b*T + t
  const int t = bt % Tn;
  const int tid = threadIdx.x;        // 0..255
  __shared__ float wlds[WIN];
  __shared__ float qd[DFT];
  __shared__ float psum[16][17];
  __shared__ float alds[16];
  if (tid < WIN) {
    const int ti = t + tid - (WIN - 1);
    wlds[tid] = (ti >= 0) ? scalar[(size_t)(bt + tid - (WIN - 1)) * Nn + n] : 0.f;
  }
  __syncthreads();
  float qf = 0.f;
#pragma unroll
  for (int i = 0; i < WIN; ++i) qf += wlds[i] * Wwq[i * DFT + tid];
  qd[tid] = qf;
  __syncthreads();
  {
    const int p = tid >> 4, seg = tid & 15;
    float part = 0.f;
#pragma unroll
    for (int j = 0; j < 16; ++j)
      part += qd[seg * 16 + j] * mem[p * DFT + seg * 16 + j];
    psum[p][seg] = part;
  }
  __syncthreads();
  if (tid < 16) {
    float s = 0.f;
#pragma unroll
    for (int j = 0; j < 16; ++j) s += psum[tid][j];
    s *= 0.0625f;  // 1/sqrt(256)
    float mx = s;
#pragma unroll
    for (int off = 8; off; off >>= 1) mx = fmaxf(mx, __shfl_xor(mx, off, 16));
    const float e = __expf(s - mx);
    float sum = e;
#pragma unroll
    for (int off = 8; off; off >>= 1) sum += __shfl_xor(sum, off, 16);
    alds[tid] = e / sum;
  }
  __syncthreads();
  float o = 0.f;
#pragma unroll
  for (int p = 0; p < Pn; ++p) o += alds[p] * val[p * DFT + tid];
  q[(size_t)mrow * Dn + tid] += o;
}

// ---------------- masked attention: one (b,kh,t) slice, 8 query rows/block ----------------
__global__ __launch_bounds__(512) void attn_kernel(
    const float* __restrict__ q, const float* __restrict__ k,
    const float* __restrict__ v, const int* __restrict__ geo_mask,
    const int* __restrict__ sem_mask, float* __restrict__ merged) {
  const int idx = blockIdx.y;          // b*96 + kh*12 + t
  const int t = idx % Tn;
  const int khead = (idx / Tn) % Kh;
  const int b = idx / (Kh * Tn);
  const int* __restrict__ mask = (khead < K_GEO) ? geo_mask : sem_mask;
  const size_t base = ((size_t)(b * Tn + t)) * Nn * Dn + (size_t)khead * dh;
  const int lane = threadIdx.x & 63;
  const int w = threadIdx.x >> 6;      // wave 0..7
  const int n = blockIdx.x * 8 + w;    // query row for this wave

  __shared__ float kv[64][65];         // k-tile then v-tile (reused)
  __shared__ float qlds[8][64];
  __shared__ float alds[8][512];

  qlds[w][lane] = q[base + (size_t)n * Dn + lane];
  const int* __restrict__ mrow = mask + (size_t)n * Nn;

  float s[8];
  float mx = -1e30f;
#pragma unroll 1
  for (int tile = 0; tile < 8; ++tile) {
    __syncthreads();
    // load k tile: keys [tile*64, tile*64+64) x 64 ch  (4096 floats, 512 threads)
    {
      const int e4 = threadIdx.x * 2;           // float4 index 0..1023, 2 per thread
#pragma unroll
      for (int u = 0; u < 2; ++u) {
        const int fi = e4 + u;                  // 0..1023
        const int kr = fi >> 4;                 // key row 0..63
        const int c4 = (fi & 15) * 4;
        const float4 kvv = *reinterpret_cast<const float4*>(
            &k[base + (size_t)(tile * 64 + kr) * Dn + c4]);
        kv[kr][c4 + 0] = kvv.x; kv[kr][c4 + 1] = kvv.y;
        kv[kr][c4 + 2] = kvv.z; kv[kr][c4 + 3] = kvv.w;
      }
    }
    __syncthreads();
    float dot = 0.f;
#pragma unroll
    for (int c = 0; c < 64; ++c) dot += qlds[w][c] * kv[lane][c];
    const int m = tile * 64 + lane;
    s[tile] = mrow[m] ? dot * 0.125f : -1e30f;
    mx = fmaxf(mx, s[tile]);
  }
  // wave softmax over 512 scores (8 per lane)
#pragma unroll
  for (int off = 32; off; off >>= 1) mx = fmaxf(mx, __shfl_xor(mx, off));
  float sum = 0.f, pr[8];
#pragma unroll
  for (int j = 0; j < 8; ++j) {
    pr[j] = mrow[j * 64 + lane] ? __expf(s[j] - mx) : 0.f;
    sum += pr[j];
  }
#pragma unroll
  for (int off = 32; off; off >>= 1) sum += __shfl_xor(sum, off);
  const float inv = sum > 0.f ? 1.f / sum : 0.f;
#pragma unroll
  for (int j = 0; j < 8; ++j) alds[w][j * 64 + lane] = pr[j] * inv;

  float acc = 0.f;
#pragma unroll 1
  for (int tile = 0; tile < 8; ++tile) {
    __syncthreads();
    {
      const int e4 = threadIdx.x * 2;
#pragma unroll
      for (int u = 0; u < 2; ++u) {
        const int fi = e4 + u;
        const int vr = fi >> 4;
        const int c4 = (fi & 15) * 4;
        const float4 vvv = *reinterpret_cast<const float4*>(
            &v[base + (size_t)(tile * 64 + vr) * Dn + c4]);
        kv[vr][c4 + 0] = vvv.x; kv[vr][c4 + 1] = vvv.y;
        kv[vr][c4 + 2] = vvv.z; kv[vr][c4 + 3] = vvv.w;
      }
    }
    __syncthreads();
    const float* __restrict__ arow = &alds[w][tile * 64];
#pragma unroll
    for (int mloc = 0; mloc < 64; ++mloc)
      acc += arow[mloc] * kv[mloc][lane];
  }
  merged[base + (size_t)n * Dn + lane] = acc;
}

// ---------------- launch ----------------
extern "C" void kernel_launch(void* const* d_in, const int* in_sizes, int n_in,
                              void* d_out, int out_size, void* d_ws, size_t ws_size,
                              hipStream_t stream) {
  const float* X        = (const float*)d_in[0];
  const float* STE      = (const float*)d_in[1];
  const int*   geo_mask = (const int*)d_in[2];
  const int*   sem_mask = (const int*)d_in[3];
  const float* PK       = (const float*)d_in[4];
  const float* Wq       = (const float*)d_in[5];
  const float* bq       = (const float*)d_in[6];
  const float* Wk       = (const float*)d_in[7];
  const float* bk       = (const float*)d_in[8];
  const float* Wv       = (const float*)d_in[9];
  const float* bv       = (const float*)d_in[10];
  const float* Wo       = (const float*)d_in[11];
  const float* bo       = (const float*)d_in[12];
  const float* Wsc      = (const float*)d_in[13];
  const float* Wwq      = (const float*)d_in[14];
  const float* Wpm      = (const float*)d_in[15];
  const float* Wpv      = (const float*)d_in[16];
  float* out = (float*)d_out;

  float* ws = (float*)d_ws;
  const size_t MD = (size_t)Mrows * Dn;   // 12,582,912
  float* q      = ws;
  float* kbuf   = ws + MD;
  float* vbuf   = ws + 2 * MD;
  float* merged = ws + 3 * MD;
  float* scalar = ws + 4 * MD;
  float* mem    = scalar + Mrows;
  float* val    = mem + Pn * DFT;

  // small precomputes
  memval_kernel<<<dim3(Pn), dim3(256), 0, stream>>>(PK, Wpm, Wpv, mem, val);
  scalar_kernel<<<dim3(Mrows / 4), dim3(256), 0, stream>>>(X, Wsc, scalar);

  // qkv GEMMs (K=1024, concat X|STE)
  dim3 ggrid(Dn / BN, Mrows / BM);
  gemm_relu_kernel<<<ggrid, dim3(256), 0, stream>>>(X, STE, Wq, bq, q, 1024);
  gemm_relu_kernel<<<ggrid, dim3(256), 0, stream>>>(X, STE, Wk, bk, kbuf, 1024);
  gemm_relu_kernel<<<ggrid, dim3(256), 0, stream>>>(X, STE, Wv, bv, vbuf, 1024);

  // DFT branch adds into q channels [0,256)
  dft_kernel<<<dim3(Mrows), dim3(256), 0, stream>>>(scalar, Wwq, mem, val, q);

  // masked attention per (b,kh,t) slice
  attn_kernel<<<dim3(Nn / 8, Bn * Kh * Tn), dim3(512), 0, stream>>>(
      q, kbuf, vbuf, geo_mask, sem_mask, merged);

  // output FC (K=512)
  gemm_relu_kernel<<<ggrid, dim3(256), 0, stream>>>(merged, merged, Wo, bo, out, 512);
}

// Round 2
// 427.040 us; speedup vs baseline: 6.4102x; 6.4102x over previous
//
#include <hip/hip_runtime.h>
#include <hip/hip_bf16.h>
#include <cstdint>

// Problem constants
#define Bn 4
#define Tn 12
#define Nn 512
#define Dn 512
#define WIN 12
#define DFT 256
#define Pn 16
#define Mrows (Bn*Tn*Nn)   // 24576

typedef __attribute__((ext_vector_type(8))) short short8;
typedef __attribute__((ext_vector_type(4))) float f32x4;

static __device__ __forceinline__ short f2bf(float x) {
  __hip_bfloat16 h = __float2bfloat16(x);
  return *reinterpret_cast<short*>(&h);
}
static __device__ __forceinline__ float bf2f(short s) {
  __hip_bfloat16 h;
  *reinterpret_cast<short*>(&h) = s;
  return __bfloat162float(h);
}
static __device__ __forceinline__ f32x4 mfma16(short8 a, short8 b, f32x4 c) {
  return __builtin_amdgcn_mfma_f32_16x16x32_bf16(a, b, c, 0, 0, 0);
}

// ---------------- cast + concat: Abf[m][0..511]=X, [512..1023]=STE ----------------
__global__ __launch_bounds__(256) void cast_concat(
    const float* __restrict__ X, const float* __restrict__ STE,
    short* __restrict__ Abf) {
  const int i = blockIdx.x * 256 + threadIdx.x;   // 0 .. 24576*128-1
  const int m = i >> 7;
  const int c4 = (i & 127) * 4;
  const float4 xv = *reinterpret_cast<const float4*>(&X[(size_t)m * 512 + c4]);
  const float4 sv = *reinterpret_cast<const float4*>(&STE[(size_t)m * 512 + c4]);
  short xo[4] = {f2bf(xv.x), f2bf(xv.y), f2bf(xv.z), f2bf(xv.w)};
  short so[4] = {f2bf(sv.x), f2bf(sv.y), f2bf(sv.z), f2bf(sv.w)};
  *reinterpret_cast<short4*>(&Abf[(size_t)m * 1024 + c4]) = make_short4(xo[0], xo[1], xo[2], xo[3]);
  *reinterpret_cast<short4*>(&Abf[(size_t)m * 1024 + 512 + c4]) = make_short4(so[0], so[1], so[2], so[3]);
}

// ---------------- cast + transpose weights: Wt[n][k] = bf16(W[k][n]) ----------------
__global__ __launch_bounds__(256) void cast_wt(
    const float* __restrict__ W, short* __restrict__ Wt, int Kt, int lKt) {
  const int i = blockIdx.x * 256 + threadIdx.x;   // 0 .. 512*Kt-1
  const int n = i >> lKt;
  const int kk = i & (Kt - 1);
  Wt[(size_t)n * Kt + kk] = f2bf(W[(size_t)kk * 512 + n]);
}

// ---------------- pack masks to bitwords: bits[n][w] covers keys w*64..w*64+63 ----------------
__global__ __launch_bounds__(256) void pack_mask(
    const int* __restrict__ geo, const int* __restrict__ sem,
    unsigned long long* __restrict__ gbits, unsigned long long* __restrict__ sbits) {
  const int lane = threadIdx.x & 63;
  const int unit = blockIdx.x * 4 + (threadIdx.x >> 6);  // 0..4095
  const int n = unit >> 3, seg = unit & 7;
  const int* __restrict__ src = blockIdx.y ? sem : geo;
  unsigned long long* __restrict__ dst = blockIdx.y ? sbits : gbits;
  const int mv = src[(size_t)n * 512 + seg * 64 + lane];
  const unsigned long long word = __ballot(mv != 0);
  if (lane == 0) dst[(size_t)n * 8 + seg] = word;
}

// ---------------- bf16 MFMA GEMM: C = relu(A @ W + b), W given transposed ----------------
// A [M x Ktot] bf16 (row stride = lda), Wt [512 x Ktot] bf16, C [M x 512]
template <typename OUT_T>
__global__ __launch_bounds__(256) void gemm_mfma(
    const short* __restrict__ A, int lda,
    const short* __restrict__ Wt, const float* __restrict__ bias,
    OUT_T* __restrict__ C, int Ktot) {
  __shared__ alignas(16) short As[128][72];
  __shared__ alignas(16) short Bs[64][72];
  const int tid = threadIdx.x, lane = tid & 63;
  const int w = tid >> 6, wm = w >> 1, wn = w & 1;
  const int lg = lane >> 4, lc = lane & 15;
  const int row0 = blockIdx.y * 128, col0 = blockIdx.x * 64;
  f32x4 acc[4][2];
#pragma unroll
  for (int i = 0; i < 4; ++i)
#pragma unroll
    for (int j = 0; j < 2; ++j) acc[i][j] = (f32x4){0.f, 0.f, 0.f, 0.f};
  for (int k0 = 0; k0 < Ktot; k0 += 64) {
    __syncthreads();
#pragma unroll
    for (int c = 0; c < 4; ++c) {
      const int r = (tid >> 3) + c * 32, c8 = (tid & 7) * 8;
      *reinterpret_cast<short8*>(&As[r][c8]) =
          *reinterpret_cast<const short8*>(&A[(size_t)(row0 + r) * lda + k0 + c8]);
    }
#pragma unroll
    for (int c = 0; c < 2; ++c) {
      const int r = (tid >> 3) + c * 32, c8 = (tid & 7) * 8;
      *reinterpret_cast<short8*>(&Bs[r][c8]) =
          *reinterpret_cast<const short8*>(&Wt[(size_t)(col0 + r) * Ktot + k0 + c8]);
    }
    __syncthreads();
#pragma unroll
    for (int kh = 0; kh < 2; ++kh) {
      const short8 b0 = *reinterpret_cast<const short8*>(&Bs[wn * 32 + lc][kh * 32 + lg * 8]);
      const short8 b1 = *reinterpret_cast<const short8*>(&Bs[wn * 32 + 16 + lc][kh * 32 + lg * 8]);
#pragma unroll
      for (int ms = 0; ms < 4; ++ms) {
        const short8 a = *reinterpret_cast<const short8*>(&As[wm * 64 + ms * 16 + lc][kh * 32 + lg * 8]);
        acc[ms][0] = mfma16(a, b0, acc[ms][0]);
        acc[ms][1] = mfma16(a, b1, acc[ms][1]);
      }
    }
  }
#pragma unroll
  for (int ms = 0; ms < 4; ++ms)
#pragma unroll
    for (int ns = 0; ns < 2; ++ns) {
      const int col = col0 + wn * 32 + ns * 16 + lc;
      const float bv = bias[col];
#pragma unroll
      for (int r = 0; r < 4; ++r) {
        const int row = row0 + wm * 64 + ms * 16 + lg * 4 + r;
        float vv = acc[ms][ns][r] + bv;
        vv = vv > 0.f ? vv : 0.f;
        if constexpr (sizeof(OUT_T) == 4)
          C[(size_t)row * 512 + col] = vv;
        else
          C[(size_t)row * 512 + col] = f2bf(vv);
      }
    }
}

// ---------------- scalar = X @ W_scalar (f32, wave per row) ----------------
__global__ __launch_bounds__(256) void scalar_kernel(
    const float* __restrict__ X, const float* __restrict__ Ws,
    float* __restrict__ out) {
  const int lane = threadIdx.x & 63;
  const int widx = threadIdx.x >> 6;
  const int row = blockIdx.x * 4 + widx;
  const float* xr = X + (size_t)row * 512;
  float d = 0.f;
#pragma unroll
  for (int h = 0; h < 2; ++h) {
    const int c = h * 256 + lane * 4;
    const float4 xv = *reinterpret_cast<const float4*>(&xr[c]);
    const float4 wv = *reinterpret_cast<const float4*>(&Ws[c]);
    d += xv.x * wv.x + xv.y * wv.y + xv.z * wv.z + xv.w * wv.w;
  }
#pragma unroll
  for (int off = 32; off; off >>= 1) d += __shfl_xor(d, off);
  if (lane == 0) out[row] = d;
}

// ---------------- mem/val = pattern_keys @ W_pm/W_pv ----------------
__global__ __launch_bounds__(256) void memval_kernel(
    const float* __restrict__ PK, const float* __restrict__ Wpm,
    const float* __restrict__ Wpv, float* __restrict__ mem,
    float* __restrict__ val) {
  const int p = blockIdx.x;
  const int f = threadIdx.x;
  float m = 0.f, v = 0.f;
#pragma unroll
  for (int i = 0; i < WIN; ++i) {
    const float pk = PK[p * WIN + i];
    m += pk * Wpm[i * DFT + f];
    v += pk * Wpv[i * DFT + f];
  }
  mem[p * DFT + f] = m;
  val[p * DFT + f] = v;
}

// ---------------- DFT branch: 8 rows/block, adds into q channels [0,256) ----------------
__global__ __launch_bounds__(256) void dft_kernel(
    const float* __restrict__ scalar, const float* __restrict__ Wwq,
    const float* __restrict__ mem, const float* __restrict__ val,
    short* __restrict__ q) {
  const int mrow0 = blockIdx.x * 8;
  const int bt = mrow0 >> 9;
  const int nb = mrow0 & 511;
  const int t = bt % Tn;
  const int tid = threadIdx.x;
  __shared__ float meml[16][256];
  __shared__ float vall[16][256];
  __shared__ float wl[8][12];
  __shared__ float qd[256];
  __shared__ float psum[16][17];
  __shared__ float al[16];
  for (int i = tid; i < 4096; i += 256) {
    meml[i >> 8][i & 255] = mem[i];
    vall[i >> 8][i & 255] = val[i];
  }
  if (tid < 96) {
    const int r = tid / 12, i = tid % 12;
    const int ti = t + i - (WIN - 1);
    wl[r][i] = (ti >= 0) ? scalar[(size_t)(bt + i - (WIN - 1)) * Nn + nb + r] : 0.f;
  }
  __syncthreads();
  for (int r = 0; r < 8; ++r) {
    float qf = 0.f;
#pragma unroll
    for (int i = 0; i < WIN; ++i) qf += wl[r][i] * Wwq[i * DFT + tid];
    qd[tid] = qf;
    __syncthreads();
    {
      const int p = tid >> 4, seg = tid & 15;
      float part = 0.f;
#pragma unroll
      for (int j = 0; j < 16; ++j)
        part += qd[seg * 16 + j] * meml[p][seg * 16 + j];
      psum[p][seg] = part;
    }
    __syncthreads();
    if (tid < 16) {
      float s = 0.f;
#pragma unroll
      for (int j = 0; j < 16; ++j) s += psum[tid][j];
      s *= 0.0625f;  // 1/sqrt(256)
      float mx = s;
#pragma unroll
      for (int off = 8; off; off >>= 1) mx = fmaxf(mx, __shfl_xor(mx, off, 16));
      const float e = __expf(s - mx);
      float sum = e;
#pragma unroll
      for (int off = 8; off; off >>= 1) sum += __shfl_xor(sum, off, 16);
      al[tid] = e / sum;
    }
    __syncthreads();
    float ov = 0.f;
#pragma unroll
    for (int p2 = 0; p2 < Pn; ++p2) ov += al[p2] * vall[p2][tid];
    const size_t qi = (size_t)(mrow0 + r) * 512 + tid;
    q[qi] = f2bf(bf2f(q[qi]) + ov);
    __syncthreads();
  }
}

// ---------------- MFMA flash attention: block = (64 q-rows, 1 head, 1 bt) ----------------
__global__ __launch_bounds__(256) void attn_mfma(
    const short* __restrict__ q, const short* __restrict__ k,
    const short* __restrict__ v, const unsigned long long* __restrict__ gbits,
    const unsigned long long* __restrict__ sbits, short* __restrict__ merged) {
  const int qt = blockIdx.x;      // 0..7 (q tile)
  const int head = blockIdx.y;    // 0..7
  const int bt = blockIdx.z;      // 0..47
  const unsigned long long* __restrict__ bits = (head < 4) ? gbits : sbits;
  const int tid = threadIdx.x, lane = tid & 63, w = tid >> 6;
  const int lg = lane >> 4, qc = lane & 15;
  const size_t rowbase = (size_t)bt * 512;
  const int cbase = head * 64;
  const int n0 = qt * 64;

  __shared__ alignas(16) short Klds[64][72];
  __shared__ alignas(16) short Vt[64][72];      // V^T with per-d XOR key swizzle
  __shared__ alignas(16) short Plds[4][16][72];
  __shared__ unsigned long long mlds[64][8];

  for (int i = tid; i < 512; i += 256)
    mlds[i >> 3][i & 7] = bits[(size_t)(n0 + (i >> 3)) * 8 + (i & 7)];

  // Q fragment (B operand of S^T): lane holds q-row n0+w*16+qc, d = kh*32+lg*8..+7
  const int qrow = n0 + w * 16 + qc;
  const short8 qf0 = *reinterpret_cast<const short8*>(&q[(rowbase + qrow) * 512 + cbase + lg * 8]);
  const short8 qf1 = *reinterpret_cast<const short8*>(&q[(rowbase + qrow) * 512 + cbase + 32 + lg * 8]);

  float m_run = -1e30f, l_run = 0.f;
  f32x4 o[4];
#pragma unroll
  for (int i = 0; i < 4; ++i) o[i] = (f32x4){0.f, 0.f, 0.f, 0.f};

  for (int ch = 0; ch < 8; ++ch) {
    __syncthreads();
    // stage K (row-major) and V^T (swizzled) for keys [ch*64, ch*64+64)
#pragma unroll
    for (int c = 0; c < 2; ++c) {
      const int idx = tid + c * 256;          // 0..511
      const int key = idx >> 3, d0 = (idx & 7) * 8;
      const size_t g = (rowbase + ch * 64 + key) * 512 + cbase + d0;
      *reinterpret_cast<short8*>(&Klds[key][d0]) = *reinterpret_cast<const short8*>(&k[g]);
      const short8 vr = *reinterpret_cast<const short8*>(&v[g]);
#pragma unroll
      for (int j = 0; j < 8; ++j) {
        const int d = d0 + j;
        Vt[d][key ^ (((d >> 3) & 7) << 3)] = vr[j];
      }
    }
    __syncthreads();

    // S^T = K · Q^T (4 key-subtiles of 16)
    const unsigned long long mword = mlds[w * 16 + qc][ch];
    float p[4][4];
    float cm = -1e30f;
#pragma unroll
    for (int s = 0; s < 4; ++s) {
      f32x4 sa = (f32x4){0.f, 0.f, 0.f, 0.f};
      const short8 a0 = *reinterpret_cast<const short8*>(&Klds[s * 16 + qc][lg * 8]);
      const short8 a1 = *reinterpret_cast<const short8*>(&Klds[s * 16 + qc][32 + lg * 8]);
      sa = mfma16(a0, qf0, sa);
      sa = mfma16(a1, qf1, sa);
#pragma unroll
      for (int r = 0; r < 4; ++r) {
        const int kb = s * 16 + lg * 4 + r;   // key index within chunk
        const bool bit = (mword >> kb) & 1ull;
        const float sv = bit ? sa[r] * 0.125f : -1e30f;
        p[s][r] = sv;
        cm = fmaxf(cm, sv);
      }
    }
    cm = fmaxf(cm, __shfl_xor(cm, 16));
    cm = fmaxf(cm, __shfl_xor(cm, 32));
    const float m_new = fmaxf(m_run, cm);
    const float alpha = __expf(m_run - m_new);
    float csum = 0.f;
#pragma unroll
    for (int s = 0; s < 4; ++s)
#pragma unroll
      for (int r = 0; r < 4; ++r) {
        const float pv = (p[s][r] > -1e29f) ? __expf(p[s][r] - m_new) : 0.f;
        csum += pv;
        Plds[w][qc][s * 16 + lg * 4 + r] = f2bf(pv);
      }
    csum += __shfl_xor(csum, 16);
    csum += __shfl_xor(csum, 32);
    l_run = l_run * alpha + csum;
    m_run = m_new;
#pragma unroll
    for (int i = 0; i < 4; ++i) o[i] *= alpha;

    // O^T += V^T · P^T
#pragma unroll
    for (int kh = 0; kh < 2; ++kh) {
      const short8 pb = *reinterpret_cast<const short8*>(&Plds[w][qc][kh * 32 + lg * 8]);
#pragma unroll
      for (int ds = 0; ds < 4; ++ds) {
        const int d = ds * 16 + qc;
        const short8 va = *reinterpret_cast<const short8*>(
            &Vt[d][(kh * 32 + lg * 8) ^ (((d >> 3) & 7) << 3)]);
        o[ds] = mfma16(va, pb, o[ds]);
      }
    }
  }
  const float inv = l_run > 0.f ? 1.f / l_run : 0.f;
#pragma unroll
  for (int ds = 0; ds < 4; ++ds)
#pragma unroll
    for (int r = 0; r < 4; ++r) {
      const int row = n0 + w * 16 + qc;
      const int col = cbase + ds * 16 + lg * 4 + r;
      merged[(rowbase + row) * 512 + col] = f2bf(o[ds][r] * inv);
    }
}

// ---------------- launch ----------------
extern "C" void kernel_launch(void* const* d_in, const int* in_sizes, int n_in,
                              void* d_out, int out_size, void* d_ws, size_t ws_size,
                              hipStream_t stream) {
  const float* X        = (const float*)d_in[0];
  const float* STE      = (const float*)d_in[1];
  const int*   geo_mask = (const int*)d_in[2];
  const int*   sem_mask = (const int*)d_in[3];
  const float* PK       = (const float*)d_in[4];
  const float* Wq       = (const float*)d_in[5];
  const float* bq       = (const float*)d_in[6];
  const float* Wk       = (const float*)d_in[7];
  const float* bk       = (const float*)d_in[8];
  const float* Wv       = (const float*)d_in[9];
  const float* bv       = (const float*)d_in[10];
  const float* Wo       = (const float*)d_in[11];
  const float* bo       = (const float*)d_in[12];
  const float* Wsc      = (const float*)d_in[13];
  const float* Wwq      = (const float*)d_in[14];
  const float* Wpm      = (const float*)d_in[15];
  const float* Wpv      = (const float*)d_in[16];
  float* out = (float*)d_out;

  char* wsb = (char*)d_ws;
  short* Abf     = (short*)(wsb);                       // 24576x1024 bf16 = 50331648 B
  short* qb      = (short*)(wsb + 50331648);            // 24576x512  bf16 = 25165824 B
  short* kb      = (short*)(wsb + 75497472);
  short* vb      = (short*)(wsb + 100663296);
  short* mergedb = (short*)(wsb + 125829120);
  short* Wqt     = (short*)(wsb + 150994944);           // 512x1024 bf16 = 1048576 B
  short* Wkt     = (short*)(wsb + 152043520);
  short* Wvt     = (short*)(wsb + 153092096);
  short* Wot     = (short*)(wsb + 154140672);           // 512x512 bf16 = 524288 B
  float* scalar  = (float*)(wsb + 154664960);           // 24576 f32
  float* mem     = (float*)(wsb + 154763264);           // 16x256 f32
  float* val     = (float*)(wsb + 154779648);
  unsigned long long* gbits = (unsigned long long*)(wsb + 154796032);  // 512x8 u64
  unsigned long long* sbits = (unsigned long long*)(wsb + 154828800);

  // precomputes / casts
  cast_concat<<<dim3(12288), dim3(256), 0, stream>>>(X, STE, Abf);
  cast_wt<<<dim3(2048), dim3(256), 0, stream>>>(Wq, Wqt, 1024, 10);
  cast_wt<<<dim3(2048), dim3(256), 0, stream>>>(Wk, Wkt, 1024, 10);
  cast_wt<<<dim3(2048), dim3(256), 0, stream>>>(Wv, Wvt, 1024, 10);
  cast_wt<<<dim3(1024), dim3(256), 0, stream>>>(Wo, Wot, 512, 9);
  pack_mask<<<dim3(1024, 2), dim3(256), 0, stream>>>(geo_mask, sem_mask, gbits, sbits);
  memval_kernel<<<dim3(Pn), dim3(256), 0, stream>>>(PK, Wpm, Wpv, mem, val);
  scalar_kernel<<<dim3(Mrows / 4), dim3(256), 0, stream>>>(X, Wsc, scalar);

  // QKV GEMMs (bf16 MFMA, K=1024)
  dim3 ggrid(8, 192);
  gemm_mfma<short><<<ggrid, dim3(256), 0, stream>>>(Abf, 1024, Wqt, bq, qb, 1024);
  gemm_mfma<short><<<ggrid, dim3(256), 0, stream>>>(Abf, 1024, Wkt, bk, kb, 1024);
  gemm_mfma<short><<<ggrid, dim3(256), 0, stream>>>(Abf, 1024, Wvt, bv, vb, 1024);

  // DFT branch adds into q channels [0,256)
  dft_kernel<<<dim3(Mrows / 8), dim3(256), 0, stream>>>(scalar, Wwq, mem, val, qb);

  // flash attention
  attn_mfma<<<dim3(8, 8, Bn * Tn), dim3(256), 0, stream>>>(qb, kb, vb, gbits, sbits, mergedb);

  // output FC (K=512), f32 out
  gemm_mfma<float><<<ggrid, dim3(256), 0, stream>>>(mergedb, 512, Wot, bo, out, 512);
}

// Round 3
// 289.503 us; speedup vs baseline: 9.4556x; 1.4751x over previous
//
#include <hip/hip_runtime.h>
#include <hip/hip_bf16.h>
#include <cstdint>

// Problem constants
#define Tn 12
#define Nn 512
#define WIN 12
#define DFT 256
#define Pn 16
#define Mrows 24576

typedef unsigned long long u64;
typedef __attribute__((ext_vector_type(8))) short short8;
typedef __attribute__((ext_vector_type(4))) float f32x4;
typedef __attribute__((address_space(1))) const void* gas1;
typedef __attribute__((address_space(3))) void* las3;

static __device__ __forceinline__ void gld16(const void* g, void* l) {
  __builtin_amdgcn_global_load_lds((gas1)g, (las3)l, 16, 0, 0);
}
static __device__ __forceinline__ short f2bf(float x) {
  __hip_bfloat16 h = __float2bfloat16(x);
  return *reinterpret_cast<short*>(&h);
}
static __device__ __forceinline__ float bf2f(short s) {
  __hip_bfloat16 h;
  *reinterpret_cast<short*>(&h) = s;
  return __bfloat162float(h);
}
static __device__ __forceinline__ f32x4 mfma16(short8 a, short8 b, f32x4 c) {
  return __builtin_amdgcn_mfma_f32_16x16x32_bf16(a, b, c, 0, 0, 0);
}

// ---------------- cast + concat: Abf[m][0..511]=X, [512..1023]=STE ----------------
__global__ __launch_bounds__(256) void cast_concat(
    const float* __restrict__ X, const float* __restrict__ STE,
    short* __restrict__ Abf) {
  const int i = blockIdx.x * 256 + threadIdx.x;   // 0..24576*64-1
  const int m = i >> 6;
  const int c8 = (i & 63) * 8;
  const float4 x0 = *reinterpret_cast<const float4*>(&X[(size_t)m * 512 + c8]);
  const float4 x1 = *reinterpret_cast<const float4*>(&X[(size_t)m * 512 + c8 + 4]);
  short8 xo;
  xo[0]=f2bf(x0.x); xo[1]=f2bf(x0.y); xo[2]=f2bf(x0.z); xo[3]=f2bf(x0.w);
  xo[4]=f2bf(x1.x); xo[5]=f2bf(x1.y); xo[6]=f2bf(x1.z); xo[7]=f2bf(x1.w);
  *reinterpret_cast<short8*>(&Abf[(size_t)m * 1024 + c8]) = xo;
  const float4 s0 = *reinterpret_cast<const float4*>(&STE[(size_t)m * 512 + c8]);
  const float4 s1 = *reinterpret_cast<const float4*>(&STE[(size_t)m * 512 + c8 + 4]);
  short8 so;
  so[0]=f2bf(s0.x); so[1]=f2bf(s0.y); so[2]=f2bf(s0.z); so[3]=f2bf(s0.w);
  so[4]=f2bf(s1.x); so[5]=f2bf(s1.y); so[6]=f2bf(s1.z); so[7]=f2bf(s1.w);
  *reinterpret_cast<short8*>(&Abf[(size_t)m * 1024 + 512 + c8]) = so;
}

// ---------------- stacked transposed weights: Wt3[n][k], n 0..1535 ----------------
__global__ __launch_bounds__(256) void prep_wqkv(
    const float* __restrict__ Wq, const float* __restrict__ Wk,
    const float* __restrict__ Wv, short* __restrict__ Wt3) {
  const int i = blockIdx.x * 256 + threadIdx.x;   // 0..1572863
  const int n = i >> 10, kk = i & 1023;
  const float* W = (n < 512) ? Wq : ((n < 1024) ? Wk : Wv);
  Wt3[(size_t)n * 1024 + kk] = f2bf(W[(size_t)kk * 512 + (n & 511)]);
}

__global__ __launch_bounds__(256) void cast_wo(
    const float* __restrict__ W, short* __restrict__ Wt) {
  const int i = blockIdx.x * 256 + threadIdx.x;   // 0..262143
  const int n = i >> 9, kk = i & 511;
  Wt[(size_t)n * 512 + kk] = f2bf(W[(size_t)kk * 512 + n]);
}

__global__ __launch_bounds__(256) void bias_cat(
    const float* __restrict__ bq, const float* __restrict__ bk,
    const float* __restrict__ bv, float* __restrict__ bqkv) {
  const int i = blockIdx.x * 256 + threadIdx.x;   // 0..1535
  bqkv[i] = (i < 512) ? bq[i] : ((i < 1024) ? bk[i - 512] : bv[i - 1024]);
}

// ---------------- pack masks to bitwords ----------------
__global__ __launch_bounds__(256) void pack_mask(
    const int* __restrict__ geo, const int* __restrict__ sem,
    u64* __restrict__ gbits, u64* __restrict__ sbits) {
  const int lane = threadIdx.x & 63;
  const int unit = blockIdx.x * 4 + (threadIdx.x >> 6);  // 0..4095
  const int n = unit >> 3, seg = unit & 7;
  const int* __restrict__ src = blockIdx.y ? sem : geo;
  u64* __restrict__ dst = blockIdx.y ? sbits : gbits;
  const int mv = src[(size_t)n * 512 + seg * 64 + lane];
  const u64 word = __ballot(mv != 0);
  if (lane == 0) dst[(size_t)n * 8 + seg] = word;
}

// ---------------- 128x128 MFMA GEMM, global_load_lds + XOR swizzle ----------------
// MODE 1: A[M x 1024] -> Cbf [M][1024] (cols<1024, relu bf16) and vT[512][M] (cols>=1024)
// MODE 0: A[M x 512]  -> Cf  [M][512]  relu f32
template <int MODE, int NCB>
__global__ __launch_bounds__(256) void gemm128(
    const short* __restrict__ A, int lda,
    const short* __restrict__ Wt, int Ktot,
    const float* __restrict__ bias,
    short* __restrict__ Cbf, short* __restrict__ vT,
    float* __restrict__ Cf) {
  __shared__ alignas(16) short As[128 * 64];
  __shared__ alignas(16) short Bs[128 * 64];
  const int tid = threadIdx.x, lane = tid & 63, w = tid >> 6;
  const int wm = w >> 1, wn = w & 1, lg = lane >> 4, lc = lane & 15;
  // XCD-bijective decode: 12 (or NCB) col-blocks of a row-panel on one XCD
  const int L = blockIdx.x;
  const int x = L & 7, j = L >> 3;
  const int rp = x * 24 + j / NCB, cb = j - (j / NCB) * NCB;
  const int row0 = rp * 128, col0 = cb * 128;
  f32x4 acc[4][4];
#pragma unroll
  for (int i = 0; i < 4; ++i)
#pragma unroll
    for (int jj = 0; jj < 4; ++jj) acc[i][jj] = (f32x4){0.f, 0.f, 0.f, 0.f};

  for (int k0 = 0; k0 < Ktot; k0 += 64) {
    __syncthreads();
    // stage: 1024 granules each; wave w covers slots [w*256, w*256+256)
#pragma unroll
    for (int c = 0; c < 4; ++c) {
      const int slot0 = w * 256 + c * 64;
      const int slot = slot0 + lane;
      const int r = slot >> 3, gs = slot & 7, g = gs ^ (r & 7);
      gld16(&A[(size_t)(row0 + r) * lda + k0 + g * 8], &As[slot0 * 8]);
      gld16(&Wt[(size_t)(col0 + r) * Ktot + k0 + g * 8], &Bs[slot0 * 8]);
    }
    __syncthreads();
#pragma unroll
    for (int kh = 0; kh < 2; ++kh) {
      short8 b[4];
#pragma unroll
      for (int ns = 0; ns < 4; ++ns) {
        const int rb = wn * 64 + ns * 16 + lc;
        b[ns] = *reinterpret_cast<const short8*>(
            &Bs[(rb * 8 + ((kh * 4 + lg) ^ (rb & 7))) * 8]);
      }
#pragma unroll
      for (int ms = 0; ms < 4; ++ms) {
        const int ra = wm * 64 + ms * 16 + lc;
        const short8 a = *reinterpret_cast<const short8*>(
            &As[(ra * 8 + ((kh * 4 + lg) ^ (ra & 7))) * 8]);
#pragma unroll
        for (int ns = 0; ns < 4; ++ns) acc[ms][ns] = mfma16(a, b[ns], acc[ms][ns]);
      }
    }
  }
  // epilogue
#pragma unroll
  for (int ms = 0; ms < 4; ++ms) {
    const int rowb = row0 + wm * 64 + ms * 16 + lg * 4;
#pragma unroll
    for (int ns = 0; ns < 4; ++ns) {
      const int colg = col0 + wn * 64 + ns * 16 + lc;
      const float bv = bias[colg];
      if constexpr (MODE == 0) {
#pragma unroll
        for (int r = 0; r < 4; ++r) {
          float vv = acc[ms][ns][r] + bv;
          Cf[(size_t)(rowb + r) * 512 + colg] = vv > 0.f ? vv : 0.f;
        }
      } else {
        if (colg < 1024) {
#pragma unroll
          for (int r = 0; r < 4; ++r) {
            float vv = acc[ms][ns][r] + bv;
            Cbf[(size_t)(rowb + r) * 1024 + colg] = f2bf(vv > 0.f ? vv : 0.f);
          }
        } else {
          short4 t4;
          float vv0 = acc[ms][ns][0] + bv; t4.x = f2bf(vv0 > 0.f ? vv0 : 0.f);
          float vv1 = acc[ms][ns][1] + bv; t4.y = f2bf(vv1 > 0.f ? vv1 : 0.f);
          float vv2 = acc[ms][ns][2] + bv; t4.z = f2bf(vv2 > 0.f ? vv2 : 0.f);
          float vv3 = acc[ms][ns][3] + bv; t4.w = f2bf(vv3 > 0.f ? vv3 : 0.f);
          *reinterpret_cast<short4*>(&vT[(size_t)(colg - 1024) * Mrows + rowb]) = t4;
        }
      }
    }
  }
}

// ---------------- scalar = X @ W_scalar (f32, wave per row) ----------------
__global__ __launch_bounds__(256) void scalar_kernel(
    const float* __restrict__ X, const float* __restrict__ Ws,
    float* __restrict__ out) {
  const int lane = threadIdx.x & 63;
  const int row = blockIdx.x * 4 + (threadIdx.x >> 6);
  const float* xr = X + (size_t)row * 512;
  float d = 0.f;
#pragma unroll
  for (int h = 0; h < 2; ++h) {
    const int c = h * 256 + lane * 4;
    const float4 xv = *reinterpret_cast<const float4*>(&xr[c]);
    const float4 wv = *reinterpret_cast<const float4*>(&Ws[c]);
    d += xv.x * wv.x + xv.y * wv.y + xv.z * wv.z + xv.w * wv.w;
  }
#pragma unroll
  for (int off = 32; off; off >>= 1) d += __shfl_xor(d, off);
  if (lane == 0) out[row] = d;
}

// ---------------- mem/val = pattern_keys @ W_pm/W_pv ----------------
__global__ __launch_bounds__(256) void memval_kernel(
    const float* __restrict__ PK, const float* __restrict__ Wpm,
    const float* __restrict__ Wpv, float* __restrict__ mem,
    float* __restrict__ val) {
  const int p = blockIdx.x, f = threadIdx.x;
  float m = 0.f, v = 0.f;
#pragma unroll
  for (int i = 0; i < WIN; ++i) {
    const float pk = PK[p * WIN + i];
    m += pk * Wpm[i * DFT + f];
    v += pk * Wpv[i * DFT + f];
  }
  mem[p * DFT + f] = m;
  val[p * DFT + f] = v;
}

// ---------------- DFT branch: 8 rows/block, adds into q channels [0,256) ----------------
__global__ __launch_bounds__(256) void dft_kernel(
    const float* __restrict__ scalar, const float* __restrict__ Wwq,
    const float* __restrict__ mem, const float* __restrict__ val,
    short* __restrict__ q) {
  const int mrow0 = blockIdx.x * 8;
  const int bt = mrow0 >> 9;
  const int nb = mrow0 & 511;
  const int t = bt % Tn;
  const int tid = threadIdx.x;
  __shared__ float meml[16][256];
  __shared__ float vall[16][256];
  __shared__ float wl[8][12];
  __shared__ float qd[256];
  __shared__ float psum[16][17];
  __shared__ float al[16];
  for (int i = tid; i < 4096; i += 256) {
    meml[i >> 8][i & 255] = mem[i];
    vall[i >> 8][i & 255] = val[i];
  }
  if (tid < 96) {
    const int r = tid / 12, i = tid % 12;
    const int ti = t + i - (WIN - 1);
    wl[r][i] = (ti >= 0) ? scalar[(size_t)(bt + i - (WIN - 1)) * Nn + nb + r] : 0.f;
  }
  __syncthreads();
  for (int r = 0; r < 8; ++r) {
    float qf = 0.f;
#pragma unroll
    for (int i = 0; i < WIN; ++i) qf += wl[r][i] * Wwq[i * DFT + tid];
    qd[tid] = qf;
    __syncthreads();
    {
      const int p = tid >> 4, seg = tid & 15;
      float part = 0.f;
#pragma unroll
      for (int jj = 0; jj < 16; ++jj)
        part += qd[seg * 16 + jj] * meml[p][seg * 16 + jj];
      psum[p][seg] = part;
    }
    __syncthreads();
    if (tid < 16) {
      float s = 0.f;
#pragma unroll
      for (int jj = 0; jj < 16; ++jj) s += psum[tid][jj];
      s *= 0.0625f;
      float mx = s;
#pragma unroll
      for (int off = 8; off; off >>= 1) mx = fmaxf(mx, __shfl_xor(mx, off, 16));
      const float e = __expf(s - mx);
      float sum = e;
#pragma unroll
      for (int off = 8; off; off >>= 1) sum += __shfl_xor(sum, off, 16);
      al[tid] = e / sum;
    }
    __syncthreads();
    float ov = 0.f;
#pragma unroll
    for (int p2 = 0; p2 < Pn; ++p2) ov += al[p2] * vall[p2][tid];
    const size_t qi = (size_t)(mrow0 + r) * 1024 + tid;
    q[qi] = f2bf(bf2f(q[qi]) + ov);
    __syncthreads();
  }
}

// ---------------- MFMA flash attention v2 ----------------
// Cm [24576][1024] = q|k, vT [512][24576]. XCD-grouped: 8 qt blocks of one
// (head,bt) land on one XCD. K and V^T staged via global_load_lds + swizzle.
__global__ __launch_bounds__(256) void attn2(
    const short* __restrict__ Cm, const short* __restrict__ vT,
    const u64* __restrict__ gbits, const u64* __restrict__ sbits,
    short* __restrict__ merged) {
  const int L = blockIdx.x;            // 0..3071
  const int x = L & 7, jj = L >> 3;    // jj 0..383
  const int g = x * 48 + (jj >> 3);    // group: same (head,bt) -> same XCD
  const int qt = jj & 7;
  const int head = g & 7, bt = g >> 3;
  const u64* __restrict__ bits = (head < 4) ? gbits : sbits;
  const int tid = threadIdx.x, lane = tid & 63, w = tid >> 6;
  const int lg = lane >> 4, qc = lane & 15;
  const size_t rowbase = (size_t)bt * 512;
  const int n0 = qt * 64;
  const int qcol = head * 64, kcol = 512 + head * 64, vrow0 = head * 64;

  __shared__ alignas(16) short Klds[64 * 64];
  __shared__ alignas(16) short Vlds[64 * 64];
  __shared__ alignas(16) short Plds[4][16][72];
  __shared__ u64 mlds[64][8];

  for (int i = tid; i < 512; i += 256)
    mlds[i >> 3][i & 7] = bits[(size_t)(n0 + (i >> 3)) * 8 + (i & 7)];

  const int qrow = n0 + w * 16 + qc;
  const short8 qf0 = *reinterpret_cast<const short8*>(
      &Cm[(rowbase + qrow) * 1024 + qcol + lg * 8]);
  const short8 qf1 = *reinterpret_cast<const short8*>(
      &Cm[(rowbase + qrow) * 1024 + qcol + 32 + lg * 8]);

  float m_run = -1e30f, l_run = 0.f;
  f32x4 o[4];
#pragma unroll
  for (int i = 0; i < 4; ++i) o[i] = (f32x4){0.f, 0.f, 0.f, 0.f};

  for (int ch = 0; ch < 8; ++ch) {
    __syncthreads();
    // stage K rows (64x64) and V^T rows (64 d x 64 keys), both swizzled
#pragma unroll
    for (int c = 0; c < 2; ++c) {
      const int slot0 = (w * 2 + c) * 64;
      const int slot = slot0 + lane;
      const int r = slot >> 3, gs = slot & 7, gg = gs ^ (r & 7);
      gld16(&Cm[(rowbase + ch * 64 + r) * 1024 + kcol + gg * 8], &Klds[slot0 * 8]);
      gld16(&vT[(size_t)(vrow0 + r) * Mrows + rowbase + ch * 64 + gg * 8],
            &Vlds[slot0 * 8]);
    }
    __syncthreads();

    // S^T = K . Q^T
    const u64 mword = mlds[w * 16 + qc][ch];
    float p[4][4];
    float cm = -1e30f;
#pragma unroll
    for (int s = 0; s < 4; ++s) {
      f32x4 sa = (f32x4){0.f, 0.f, 0.f, 0.f};
      const int rk = s * 16 + qc;
      const short8 a0 = *reinterpret_cast<const short8*>(
          &Klds[(rk * 8 + (lg ^ (rk & 7))) * 8]);
      const short8 a1 = *reinterpret_cast<const short8*>(
          &Klds[(rk * 8 + ((4 + lg) ^ (rk & 7))) * 8]);
      sa = mfma16(a0, qf0, sa);
      sa = mfma16(a1, qf1, sa);
#pragma unroll
      for (int r = 0; r < 4; ++r) {
        const int kb = s * 16 + lg * 4 + r;
        const bool bit = (mword >> kb) & 1ull;
        const float sv = bit ? sa[r] * 0.125f : -1e30f;
        p[s][r] = sv;
        cm = fmaxf(cm, sv);
      }
    }
    cm = fmaxf(cm, __shfl_xor(cm, 16));
    cm = fmaxf(cm, __shfl_xor(cm, 32));
    if (__any(cm > m_run)) {           // T13-style: skip rescale when max unchanged
      const float m_new = fmaxf(m_run, cm);
      const float alpha = __expf(m_run - m_new);
      l_run *= alpha;
#pragma unroll
      for (int i = 0; i < 4; ++i) o[i] *= alpha;
      m_run = m_new;
    }
    float csum = 0.f;
#pragma unroll
    for (int s = 0; s < 4; ++s) {
      short4 p4;
      float pv0 = (p[s][0] > -1e29f) ? __expf(p[s][0] - m_run) : 0.f;
      float pv1 = (p[s][1] > -1e29f) ? __expf(p[s][1] - m_run) : 0.f;
      float pv2 = (p[s][2] > -1e29f) ? __expf(p[s][2] - m_run) : 0.f;
      float pv3 = (p[s][3] > -1e29f) ? __expf(p[s][3] - m_run) : 0.f;
      csum += pv0 + pv1 + pv2 + pv3;
      p4.x = f2bf(pv0); p4.y = f2bf(pv1); p4.z = f2bf(pv2); p4.w = f2bf(pv3);
      *reinterpret_cast<short4*>(&Plds[w][qc][s * 16 + lg * 4]) = p4;
    }
    csum += __shfl_xor(csum, 16);
    csum += __shfl_xor(csum, 32);
    l_run += csum;

    // O^T += V^T . P^T
#pragma unroll
    for (int kh = 0; kh < 2; ++kh) {
      const short8 pb = *reinterpret_cast<const short8*>(
          &Plds[w][qc][kh * 32 + lg * 8]);
#pragma unroll
      for (int ds = 0; ds < 4; ++ds) {
        const int rd = ds * 16 + qc;
        const short8 va = *reinterpret_cast<const short8*>(
            &Vlds[(rd * 8 + ((kh * 4 + lg) ^ (rd & 7))) * 8]);
        o[ds] = mfma16(va, pb, o[ds]);
      }
    }
  }
  const float inv = l_run > 0.f ? 1.f / l_run : 0.f;
#pragma unroll
  for (int ds = 0; ds < 4; ++ds) {
    short4 t4;
    t4.x = f2bf(o[ds][0] * inv);
    t4.y = f2bf(o[ds][1] * inv);
    t4.z = f2bf(o[ds][2] * inv);
    t4.w = f2bf(o[ds][3] * inv);
    *reinterpret_cast<short4*>(
        &merged[(rowbase + qrow) * 512 + head * 64 + ds * 16 + lg * 4]) = t4;
  }
}

// ---------------- launch ----------------
extern "C" void kernel_launch(void* const* d_in, const int* in_sizes, int n_in,
                              void* d_out, int out_size, void* d_ws, size_t ws_size,
                              hipStream_t stream) {
  const float* X        = (const float*)d_in[0];
  const float* STE      = (const float*)d_in[1];
  const int*   geo_mask = (const int*)d_in[2];
  const int*   sem_mask = (const int*)d_in[3];
  const float* PK       = (const float*)d_in[4];
  const float* Wq       = (const float*)d_in[5];
  const float* bq       = (const float*)d_in[6];
  const float* Wk       = (const float*)d_in[7];
  const float* bk       = (const float*)d_in[8];
  const float* Wv       = (const float*)d_in[9];
  const float* bv       = (const float*)d_in[10];
  const float* Wo       = (const float*)d_in[11];
  const float* bo       = (const float*)d_in[12];
  const float* Wsc      = (const float*)d_in[13];
  const float* Wwq      = (const float*)d_in[14];
  const float* Wpm      = (const float*)d_in[15];
  const float* Wpv      = (const float*)d_in[16];
  float* out = (float*)d_out;

  char* wsb = (char*)d_ws;
  short* Abf     = (short*)(wsb);                    // 24576x1024 bf16 (50331648 B)
  short* mergedb = (short*)(wsb);                    // aliases Abf (dead after QKV GEMM)
  short* Cm      = (short*)(wsb + 50331648);         // 24576x1024 bf16: q|k
  short* vT      = (short*)(wsb + 100663296);        // 512x24576 bf16
  short* Wt3     = (short*)(wsb + 125829120);        // 1536x1024 bf16
  short* Wot     = (short*)(wsb + 128974848);        // 512x512 bf16
  float* bqkv    = (float*)(wsb + 129499136);        // 1536 f32
  float* scalar  = (float*)(wsb + 129505280);        // 24576 f32
  float* mem     = (float*)(wsb + 129603584);
  float* val     = (float*)(wsb + 129619968);
  u64*   gbits   = (u64*)  (wsb + 129636352);
  u64*   sbits   = (u64*)  (wsb + 129669120);

  cast_concat<<<dim3(6144), dim3(256), 0, stream>>>(X, STE, Abf);
  prep_wqkv<<<dim3(6144), dim3(256), 0, stream>>>(Wq, Wk, Wv, Wt3);
  cast_wo<<<dim3(1024), dim3(256), 0, stream>>>(Wo, Wot);
  bias_cat<<<dim3(6), dim3(256), 0, stream>>>(bq, bk, bv, bqkv);
  pack_mask<<<dim3(1024, 2), dim3(256), 0, stream>>>(geo_mask, sem_mask, gbits, sbits);
  memval_kernel<<<dim3(Pn), dim3(256), 0, stream>>>(PK, Wpm, Wpv, mem, val);
  scalar_kernel<<<dim3(Mrows / 4), dim3(256), 0, stream>>>(X, Wsc, scalar);

  // merged QKV GEMM: M=24576, K=1024, N=1536 (writes Cm q|k + vT transposed)
  gemm128<1, 12><<<dim3(2304), dim3(256), 0, stream>>>(
      Abf, 1024, Wt3, 1024, bqkv, Cm, vT, nullptr);

  // DFT branch adds into q channels [0,256)
  dft_kernel<<<dim3(Mrows / 8), dim3(256), 0, stream>>>(scalar, Wwq, mem, val, Cm);

  // flash attention
  attn2<<<dim3(3072), dim3(256), 0, stream>>>(Cm, vT, gbits, sbits, mergedb);

  // output FC: M=24576, K=512, N=512, f32 out
  gemm128<0, 4><<<dim3(768), dim3(256), 0, stream>>>(
      mergedb, 512, Wot, 512, bo, nullptr, nullptr, out);
}